// Round 1
// baseline (2713.471 us; speedup 1.0000x reference)
//
#include <hip/hip_runtime.h>
#include <math.h>

#define Nn 30000
#define INF_DIM 768
#define CH 128
#define HEADS 4
#define DHH 128
#define RR 3
#define EE 80000

#define BM 64
#define BN 64
#define BK 32

// ---------------------------------------------------------------------------
// Generic fp32 GEMM core: C_tile = A[m0.., :K] @ B[:, n0..]
// A row-major [M, lda], B row-major [K, ldb]. K % 32 == 0, N-tile always full.
// ---------------------------------------------------------------------------
__device__ __forceinline__ void gemm_accumulate(
    const float* __restrict__ A, int lda,
    const float* __restrict__ B, int ldb,
    int M, int K, int m0, int n0,
    float (&acc)[4][4],
    float (*As)[BK + 4], float (*Bs)[BN])
{
    const int tid = threadIdx.x;
    const int tm = tid >> 4, tn = tid & 15;
    const int la_row = tid >> 3;      // 0..31
    const int la_c4  = tid & 7;       // 0..7  -> col la_c4*4
    const int lb_row = tid >> 4;      // 0..15
    const int lb_c4  = tid & 15;      // 0..15 -> col lb_c4*4

    for (int k0 = 0; k0 < K; k0 += BK) {
        #pragma unroll
        for (int half = 0; half < 2; half++) {
            int r = la_row + half * 32;
            int gr = m0 + r;
            float4 fa;
            if (gr < M) fa = *(const float4*)(A + (size_t)gr * lda + k0 + la_c4 * 4);
            else        fa = make_float4(0.f, 0.f, 0.f, 0.f);
            *(float4*)(&As[r][la_c4 * 4]) = fa;
        }
        #pragma unroll
        for (int half = 0; half < 2; half++) {
            int r = lb_row + half * 16;
            float4 fb = *(const float4*)(B + (size_t)(k0 + r) * ldb + n0 + lb_c4 * 4);
            *(float4*)(&Bs[r][lb_c4 * 4]) = fb;
        }
        __syncthreads();
        #pragma unroll
        for (int kk = 0; kk < BK; kk++) {
            float4 bv = *(const float4*)(&Bs[kk][tn * 4]);
            float a0 = As[tm * 4 + 0][kk];
            float a1 = As[tm * 4 + 1][kk];
            float a2 = As[tm * 4 + 2][kk];
            float a3 = As[tm * 4 + 3][kk];
            acc[0][0] += a0 * bv.x; acc[0][1] += a0 * bv.y; acc[0][2] += a0 * bv.z; acc[0][3] += a0 * bv.w;
            acc[1][0] += a1 * bv.x; acc[1][1] += a1 * bv.y; acc[1][2] += a1 * bv.z; acc[1][3] += a1 * bv.w;
            acc[2][0] += a2 * bv.x; acc[2][1] += a2 * bv.y; acc[2][2] += a2 * bv.z; acc[2][3] += a2 * bv.w;
            acc[3][0] += a3 * bv.x; acc[3][1] += a3 * bv.y; acc[3][2] += a3 * bv.z; acc[3][3] += a3 * bv.w;
        }
        __syncthreads();
    }
}

// act: 0 = none, 1 = leaky relu (0.01)
__global__ __launch_bounds__(256) void gemm_bias_act(
    const float* __restrict__ A, int lda,
    const float* __restrict__ B, int ldb,
    const float* __restrict__ bias,
    float* __restrict__ C, int ldc,
    int M, int N, int K, int act)
{
    __shared__ float As[BM][BK + 4];
    __shared__ float Bs[BK][BN];
    int m0 = blockIdx.y * BM, n0 = blockIdx.x * BN;
    float acc[4][4] = {};
    gemm_accumulate(A, lda, B, ldb, M, K, m0, n0, acc, As, Bs);
    int tm = threadIdx.x >> 4, tn = threadIdx.x & 15;
    #pragma unroll
    for (int i = 0; i < 4; i++) {
        int gr = m0 + tm * 4 + i;
        if (gr >= M) continue;
        #pragma unroll
        for (int j = 0; j < 4; j++) {
            int gc = n0 + tn * 4 + j;
            float v = acc[i][j] + bias[gc];
            if (act == 1) v = (v >= 0.f) ? v : 0.01f * v;
            C[(size_t)gr * ldc + gc] = v;
        }
    }
}

// Gate + combine: Z = sigmoid(U@gW[0:128] + h@gW[128:256] + gb)
// Hm_out[n, c] = tanh(U)*Z + h*(1-Z)   (Hm_out passed pre-offset by r*128, ld=384)
__global__ __launch_bounds__(256) void gate_combine(
    const float* __restrict__ U,   // [M,128]
    const float* __restrict__ H,   // [M,128]
    const float* __restrict__ gW,  // [256,128]
    const float* __restrict__ gb,  // [128]
    float* __restrict__ HmOut,     // base + r*128, row stride 384
    int M)
{
    __shared__ float As[BM][BK + 4];
    __shared__ float Bs[BK][BN];
    int m0 = blockIdx.y * BM, n0 = blockIdx.x * BN;
    const int tid = threadIdx.x;
    const int tm = tid >> 4, tn = tid & 15;
    const int la_row = tid >> 3, la_c4 = tid & 7;
    const int lb_row = tid >> 4, lb_c4 = tid & 15;
    float acc[4][4] = {};

    for (int k0 = 0; k0 < 256; k0 += BK) {
        const float* Asrc = (k0 < 128) ? U : H;
        int kc = (k0 < 128) ? k0 : (k0 - 128);
        #pragma unroll
        for (int half = 0; half < 2; half++) {
            int r = la_row + half * 32;
            int gr = m0 + r;
            float4 fa;
            if (gr < M) fa = *(const float4*)(Asrc + (size_t)gr * 128 + kc + la_c4 * 4);
            else        fa = make_float4(0.f, 0.f, 0.f, 0.f);
            *(float4*)(&As[r][la_c4 * 4]) = fa;
        }
        #pragma unroll
        for (int half = 0; half < 2; half++) {
            int r = lb_row + half * 16;
            float4 fb = *(const float4*)(gW + (size_t)(k0 + r) * 128 + n0 + lb_c4 * 4);
            *(float4*)(&Bs[r][lb_c4 * 4]) = fb;
        }
        __syncthreads();
        #pragma unroll
        for (int kk = 0; kk < BK; kk++) {
            float4 bv = *(const float4*)(&Bs[kk][tn * 4]);
            float a0 = As[tm * 4 + 0][kk];
            float a1 = As[tm * 4 + 1][kk];
            float a2 = As[tm * 4 + 2][kk];
            float a3 = As[tm * 4 + 3][kk];
            acc[0][0] += a0 * bv.x; acc[0][1] += a0 * bv.y; acc[0][2] += a0 * bv.z; acc[0][3] += a0 * bv.w;
            acc[1][0] += a1 * bv.x; acc[1][1] += a1 * bv.y; acc[1][2] += a1 * bv.z; acc[1][3] += a1 * bv.w;
            acc[2][0] += a2 * bv.x; acc[2][1] += a2 * bv.y; acc[2][2] += a2 * bv.z; acc[2][3] += a2 * bv.w;
            acc[3][0] += a3 * bv.x; acc[3][1] += a3 * bv.y; acc[3][2] += a3 * bv.z; acc[3][3] += a3 * bv.w;
        }
        __syncthreads();
    }
    #pragma unroll
    for (int i = 0; i < 4; i++) {
        int gr = m0 + tm * 4 + i;
        if (gr >= M) continue;
        #pragma unroll
        for (int j = 0; j < 4; j++) {
            int gc = n0 + tn * 4 + j;
            float g = acc[i][j] + gb[gc];
            float z = 1.f / (1.f + __expf(-g));
            float u = U[(size_t)gr * 128 + gc];
            float hh = H[(size_t)gr * 128 + gc];
            HmOut[(size_t)gr * 384 + gc] = tanhf(u) * z + hh * (1.f - z);
        }
    }
}

// Semantic scoring: for z=(h,r): scores[z] += sum_n sum_o tanh((Hm[:,r]@sW1[h])[n,o]+sb1[h,o])*sw2[h,o]
__global__ __launch_bounds__(256) void semantic_scores(
    const float* __restrict__ Hm,   // [M, 384]
    const float* __restrict__ sW1,  // [4,128,128]
    const float* __restrict__ sb1,  // [4,128]
    const float* __restrict__ sw2,  // [4,128]
    float* __restrict__ scores,     // [12]
    int M)
{
    __shared__ float As[BM][BK + 4];
    __shared__ float Bs[BK][BN];
    __shared__ float red[256];
    int z = blockIdx.z;
    int hh = z / 3, r = z - hh * 3;
    const float* A = Hm + r * 128;
    const float* B = sW1 + hh * 128 * 128;
    int m0 = blockIdx.y * BM, n0 = blockIdx.x * BN;
    float acc[4][4] = {};
    gemm_accumulate(A, 384, B, 128, M, 128, m0, n0, acc, As, Bs);
    int tid = threadIdx.x;
    int tm = tid >> 4, tn = tid & 15;
    float local = 0.f;
    #pragma unroll
    for (int i = 0; i < 4; i++) {
        int gr = m0 + tm * 4 + i;
        if (gr >= M) continue;
        #pragma unroll
        for (int j = 0; j < 4; j++) {
            int gc = n0 + tn * 4 + j;
            float t = tanhf(acc[i][j] + sb1[hh * 128 + gc]);
            local += t * sw2[hh * 128 + gc];
        }
    }
    red[tid] = local;
    __syncthreads();
    for (int s = 128; s > 0; s >>= 1) {
        if (tid < s) red[tid] += red[tid + s];
        __syncthreads();
    }
    if (tid == 0) atomicAdd(&scores[z], red[0]);
}

__global__ void compute_w_kernel(const float* __restrict__ scores, float* __restrict__ w, float invN)
{
    if (blockIdx.x == 0 && threadIdx.x == 0) {
        float wr[3] = {0.f, 0.f, 0.f};
        for (int h = 0; h < 4; h++) {
            float s0 = scores[h * 3 + 0] * invN;
            float s1 = scores[h * 3 + 1] * invN;
            float s2 = scores[h * 3 + 2] * invN;
            float mx = fmaxf(s0, fmaxf(s1, s2));
            float e0 = __expf(s0 - mx), e1 = __expf(s1 - mx), e2 = __expf(s2 - mx);
            float inv = 1.f / (e0 + e1 + e2);
            wr[0] += 0.25f * e0 * inv;
            wr[1] += 0.25f * e1 * inv;
            wr[2] += 0.25f * e2 * inv;
        }
        w[0] = wr[0]; w[1] = wr[1]; w[2] = wr[2];
    }
}

__global__ void mix_kernel(const float* __restrict__ Hm, const float* __restrict__ w,
                           float* __restrict__ h, int total)
{
    int i = blockIdx.x * blockDim.x + threadIdx.x;
    if (i >= total) return;
    int n = i >> 7, c = i & 127;
    const float* row = Hm + (size_t)n * 384;
    h[i] = w[0] * row[c] + w[1] * row[128 + c] + w[2] * row[256 + c];
}

// --------------------------- CSR build ------------------------------------
__global__ void zero_i32_kernel(int* __restrict__ p, int n)
{
    int i = blockIdx.x * blockDim.x + threadIdx.x;
    if (i < n) p[i] = 0;
}

__global__ void hist_kernel(const int* __restrict__ dst, int E, int* __restrict__ cnt)
{
    int e = blockIdx.x * blockDim.x + threadIdx.x;
    if (e < E) atomicAdd(&cnt[dst[e]], 1);
}

__global__ __launch_bounds__(1024) void scan_kernel(const int* __restrict__ cnt,
                                                    int* __restrict__ rowptr, int n)
{
    __shared__ int part[1024];
    int tid = threadIdx.x;
    int per = (n + 1023) >> 10;
    int base = tid * per;
    int s = 0;
    for (int i = 0; i < per; i++) {
        int idx = base + i;
        if (idx < n) s += cnt[idx];
    }
    part[tid] = s;
    __syncthreads();
    for (int off = 1; off < 1024; off <<= 1) {
        int val = (tid >= off) ? part[tid - off] : 0;
        __syncthreads();
        part[tid] += val;
        __syncthreads();
    }
    int excl = (tid == 0) ? 0 : part[tid - 1];
    for (int i = 0; i < per; i++) {
        int idx = base + i;
        if (idx < n) { rowptr[idx] = excl; excl += cnt[idx]; }
    }
    if (tid == 1023) rowptr[n] = part[1023];
}

__global__ void scatter_kernel(const int* __restrict__ esrc, const int* __restrict__ edst, int E,
                               const int* __restrict__ rowptr, int* __restrict__ fill,
                               int* __restrict__ col)
{
    int e = blockIdx.x * blockDim.x + threadIdx.x;
    if (e < E) {
        int d = edst[e];
        int pos = rowptr[d] + atomicAdd(&fill[d], 1);
        col[pos] = esrc[e];
    }
}

// --------------------------- attention ------------------------------------
// One wave per dst node. q/k/v: [N, 4*128] flat. US holds S on input; U written in place.
__global__ __launch_bounds__(256) void attn_kernel(
    const float* __restrict__ q, const float* __restrict__ k, const float* __restrict__ v,
    const int* __restrict__ rowptr, const int* __restrict__ col,
    float* __restrict__ US, int N)
{
    int wid = ((blockIdx.x * blockDim.x + threadIdx.x) >> 6);
    int lane = threadIdx.x & 63;
    if (wid >= N) return;
    int n = wid;
    int beg = rowptr[n], end = rowptr[n + 1];

    float qf[8];
    const float* qrow = q + (size_t)n * 512;
    #pragma unroll
    for (int j = 0; j < 8; j++) qf[j] = qrow[j * 64 + lane];

    float m0 = -INFINITY, m1 = -INFINITY, m2 = -INFINITY, m3 = -INFINITY;
    float s0 = 0.f, s1 = 0.f, s2 = 0.f, s3 = 0.f;
    float acc[8] = {0.f, 0.f, 0.f, 0.f, 0.f, 0.f, 0.f, 0.f};
    const float scale = 0.088388347648318447f; // 1/sqrt(128)

    for (int i = beg; i < end; i++) {
        int src = col[i];
        const float* krow = k + (size_t)src * 512;
        const float* vrow = v + (size_t)src * 512;
        float kf[8], vf[8];
        #pragma unroll
        for (int j = 0; j < 8; j++) kf[j] = krow[j * 64 + lane];
        #pragma unroll
        for (int j = 0; j < 8; j++) vf[j] = vrow[j * 64 + lane];
        float p0 = qf[0] * kf[0] + qf[1] * kf[1];
        float p1 = qf[2] * kf[2] + qf[3] * kf[3];
        float p2 = qf[4] * kf[4] + qf[5] * kf[5];
        float p3 = qf[6] * kf[6] + qf[7] * kf[7];
        #pragma unroll
        for (int off = 32; off > 0; off >>= 1) {
            p0 += __shfl_xor(p0, off);
            p1 += __shfl_xor(p1, off);
            p2 += __shfl_xor(p2, off);
            p3 += __shfl_xor(p3, off);
        }
        float l0 = p0 * scale, l1 = p1 * scale, l2 = p2 * scale, l3 = p3 * scale;

        float nm, sc, pe;
        nm = fmaxf(m0, l0); sc = __expf(m0 - nm); pe = __expf(l0 - nm);
        s0 = s0 * sc + pe; acc[0] = acc[0] * sc + pe * vf[0]; acc[1] = acc[1] * sc + pe * vf[1]; m0 = nm;
        nm = fmaxf(m1, l1); sc = __expf(m1 - nm); pe = __expf(l1 - nm);
        s1 = s1 * sc + pe; acc[2] = acc[2] * sc + pe * vf[2]; acc[3] = acc[3] * sc + pe * vf[3]; m1 = nm;
        nm = fmaxf(m2, l2); sc = __expf(m2 - nm); pe = __expf(l2 - nm);
        s2 = s2 * sc + pe; acc[4] = acc[4] * sc + pe * vf[4]; acc[5] = acc[5] * sc + pe * vf[5]; m2 = nm;
        nm = fmaxf(m3, l3); sc = __expf(m3 - nm); pe = __expf(l3 - nm);
        s3 = s3 * sc + pe; acc[6] = acc[6] * sc + pe * vf[6]; acc[7] = acc[7] * sc + pe * vf[7]; m3 = nm;
    }

    float i0 = (s0 > 0.f) ? 1.f / s0 : 0.f;
    float i1 = (s1 > 0.f) ? 1.f / s1 : 0.f;
    float i2 = (s2 > 0.f) ? 1.f / s2 : 0.f;
    float i3 = (s3 > 0.f) ? 1.f / s3 : 0.f;
    float u_lo = 0.25f * (acc[0] * i0 + acc[2] * i1 + acc[4] * i2 + acc[6] * i3);
    float u_hi = 0.25f * (acc[1] * i0 + acc[3] * i1 + acc[5] * i2 + acc[7] * i3);
    float* urow = US + (size_t)n * 128;
    urow[lane]      += u_lo;
    urow[64 + lane] += u_hi;
}

// --------------------------- classifier -----------------------------------
__global__ void clf_kernel(const float* __restrict__ t, const float* __restrict__ W,
                           const float* __restrict__ b, float* __restrict__ out, int M)
{
    int n = blockIdx.x * blockDim.x + threadIdx.x;
    if (n >= M) return;
    const float* row = t + (size_t)n * 128;
    float a0 = b[0], a1 = b[1];
    #pragma unroll
    for (int kk = 0; kk < 128; kk++) {
        float a = row[kk];
        a0 += a * W[kk * 2];
        a1 += a * W[kk * 2 + 1];
    }
    out[n * 2] = a0;
    out[n * 2 + 1] = a1;
}

// ---------------------------------------------------------------------------
extern "C" void kernel_launch(void* const* d_in, const int* in_sizes, int n_in,
                              void* d_out, int out_size, void* d_ws, size_t ws_size,
                              hipStream_t stream)
{
    const float* x      = (const float*)d_in[0];
    const int*   edges  = (const int*)d_in[1];
    const float* lin1_W = (const float*)d_in[2];
    const float* lin1_b = (const float*)d_in[3];
    // Layer param blocks: l1 at 4..16, l2 at 17..29
    const int L0 = 4, L1 = 17;
    const float* lin2_W = (const float*)d_in[30];
    const float* lin2_b = (const float*)d_in[31];
    const float* clf_W  = (const float*)d_in[32];
    const float* clf_b  = (const float*)d_in[33];
    float* out = (float*)d_out;

    // workspace layout
    char* w = (char*)d_ws;
    size_t off = 0;
    auto alloc = [&](size_t bytes) { void* p = w + off; off = (off + bytes + 255) & ~(size_t)255; return p; };
    float* h   = (float*)alloc((size_t)Nn * 128 * 4);
    float* qb  = (float*)alloc((size_t)Nn * 512 * 4);
    float* kb  = (float*)alloc((size_t)Nn * 512 * 4);
    float* vb  = (float*)alloc((size_t)Nn * 512 * 4);
    float* Sb  = (float*)alloc((size_t)Nn * 128 * 4);
    float* Hm  = (float*)alloc((size_t)Nn * 384 * 4);
    int* rowptr = (int*)alloc((size_t)(Nn + 1) * 4);
    int* cnt    = (int*)alloc((size_t)Nn * 4);
    int* colb   = (int*)alloc((size_t)EE * 4);
    float* scores = (float*)alloc(12 * 4);
    float* wmix   = (float*)alloc(3 * 4);

    const int MT = (Nn + BM - 1) / BM;     // 469
    dim3 blk(256);

    // lin1: h = lrelu(x @ lin1_W + lin1_b)
    gemm_bias_act<<<dim3(CH / BN, MT), blk, 0, stream>>>(
        x, INF_DIM, lin1_W, CH, lin1_b, h, CH, Nn, CH, INF_DIM, 1);

    for (int l = 0; l < 2; l++) {
        int base = (l == 0) ? L0 : L1;
        const float* Wq  = (const float*)d_in[base + 0];
        const float* bq  = (const float*)d_in[base + 1];
        const float* Wk  = (const float*)d_in[base + 2];
        const float* bk  = (const float*)d_in[base + 3];
        const float* Wv  = (const float*)d_in[base + 4];
        const float* bv  = (const float*)d_in[base + 5];
        const float* Ws  = (const float*)d_in[base + 6];
        const float* bs  = (const float*)d_in[base + 7];
        const float* gW  = (const float*)d_in[base + 8];
        const float* gb  = (const float*)d_in[base + 9];
        const float* sW1 = (const float*)d_in[base + 10];
        const float* sb1 = (const float*)d_in[base + 11];
        const float* sw2 = (const float*)d_in[base + 12];

        for (int r = 0; r < RR; r++) {
            const int HD = HEADS * DHH; // 512
            // q/k/v GEMMs
            gemm_bias_act<<<dim3(HD / BN, MT), blk, 0, stream>>>(
                h, CH, Wq + (size_t)r * CH * HD, HD, bq + r * HD, qb, HD, Nn, HD, CH, 0);
            gemm_bias_act<<<dim3(HD / BN, MT), blk, 0, stream>>>(
                h, CH, Wk + (size_t)r * CH * HD, HD, bk + r * HD, kb, HD, Nn, HD, CH, 0);
            gemm_bias_act<<<dim3(HD / BN, MT), blk, 0, stream>>>(
                h, CH, Wv + (size_t)r * CH * HD, HD, bv + r * HD, vb, HD, Nn, HD, CH, 0);
            // S = h @ Ws + bs  (into Sb; attention adds agg-mean in place)
            gemm_bias_act<<<dim3(CH / BN, MT), blk, 0, stream>>>(
                h, CH, Ws + (size_t)r * CH * DHH, DHH, bs + r * DHH, Sb, DHH, Nn, DHH, CH, 0);

            // CSR build by dst
            const int* esrc = edges + (size_t)r * 2 * EE;
            const int* edst = esrc + EE;
            zero_i32_kernel<<<(Nn + 255) / 256, blk, 0, stream>>>(cnt, Nn);
            hist_kernel<<<(EE + 255) / 256, blk, 0, stream>>>(edst, EE, cnt);
            scan_kernel<<<1, 1024, 0, stream>>>(cnt, rowptr, Nn);
            zero_i32_kernel<<<(Nn + 255) / 256, blk, 0, stream>>>(cnt, Nn);
            scatter_kernel<<<(EE + 255) / 256, blk, 0, stream>>>(esrc, edst, EE, rowptr, cnt, colb);

            // attention: U = mean_h softmax-agg + S   (in place in Sb)
            attn_kernel<<<(Nn + 3) / 4, blk, 0, stream>>>(qb, kb, vb, rowptr, colb, Sb, Nn);

            // gate + combine -> Hm[:, r, :]
            gate_combine<<<dim3(CH / BN, MT), blk, 0, stream>>>(
                Sb, h, gW, gb, Hm + r * CH, Nn);
        }

        // semantic attention
        zero_i32_kernel<<<1, 64, 0, stream>>>((int*)scores, 12);
        semantic_scores<<<dim3(CH / BN, MT, 12), blk, 0, stream>>>(Hm, sW1, sb1, sw2, scores, Nn);
        compute_w_kernel<<<1, 64, 0, stream>>>(scores, wmix, 1.f / (float)Nn);
        mix_kernel<<<(Nn * 128 + 255) / 256, blk, 0, stream>>>(Hm, wmix, h, Nn * 128);
    }

    // lin2 + lrelu -> Sb
    gemm_bias_act<<<dim3(CH / BN, MT), blk, 0, stream>>>(
        h, CH, lin2_W, CH, lin2_b, Sb, CH, Nn, CH, CH, 1);
    // classifier
    clf_kernel<<<(Nn + 255) / 256, blk, 0, stream>>>(Sb, clf_W, clf_b, out, Nn);
}

// Round 2
// 1799.893 us; speedup vs baseline: 1.5076x; 1.5076x over previous
//
#include <hip/hip_runtime.h>
#include <math.h>

#define Nn 30000
#define INF_DIM 768
#define CH 128
#define RR 3
#define EE 80000

#define SAP 72        // padded LDS row stride (bf16 elems) for 64-col tiles
#define KBIG 0x40000000

typedef __attribute__((ext_vector_type(8))) short bf16x8;
typedef __attribute__((ext_vector_type(4))) float f32x4;

__device__ __forceinline__ unsigned short f2bf(float f) {
    union { float f; unsigned u; } v; v.f = f;
    unsigned r = v.u + 0x7fff + ((v.u >> 16) & 1);
    return (unsigned short)(r >> 16);
}
__device__ __forceinline__ float bf2f(short h) {
    union { unsigned u; float f; } v;
    v.u = ((unsigned)(unsigned short)h) << 16;
    return v.f;
}

// ---------------------------------------------------------------------------
// MFMA GEMM core. A: bf16 [M, lda] row-major (split at ksplit -> A2).
// Bt: bf16 [N, K] row-major (pre-transposed). Block tile 128x128, BK=64.
// 4 waves, each 64x64 via 4x4 grid of 16x16x32 MFMAs.
// ---------------------------------------------------------------------------
__device__ __forceinline__ void mfma_core(
    const short* __restrict__ A, const short* __restrict__ A2, int lda, int ksplit,
    const short* __restrict__ Bt,
    int M, int K, int m0, int n0,
    short* As, short* Bs, f32x4 (&acc)[4][4])
{
    const int t = threadIdx.x;
    const int srow = t >> 3;          // 0..31
    const int scol = (t & 7) << 3;    // 0..56 step 8
    const int lane = t & 63;
    const int wave = t >> 6;
    const int wm = (wave >> 1) << 6;
    const int wn = (wave & 1) << 6;
    const int fr = lane & 15;
    const int quad = lane >> 4;

    for (int k0 = 0; k0 < K; k0 += 64) {
        const short* Abase; int kk0;
        if (k0 < ksplit) { Abase = A; kk0 = k0; }
        else             { Abase = A2; kk0 = k0 - ksplit; }
        #pragma unroll
        for (int rr = 0; rr < 4; rr++) {
            int r = srow + rr * 32;
            int gr = m0 + r;
            bf16x8 va = {0, 0, 0, 0, 0, 0, 0, 0};
            if (gr < M) va = *(const bf16x8*)(Abase + (size_t)gr * lda + kk0 + scol);
            *(bf16x8*)(As + r * SAP + scol) = va;
        }
        #pragma unroll
        for (int rr = 0; rr < 4; rr++) {
            int r = srow + rr * 32;
            bf16x8 vb = *(const bf16x8*)(Bt + (size_t)(n0 + r) * K + k0 + scol);
            *(bf16x8*)(Bs + r * SAP + scol) = vb;
        }
        __syncthreads();
        #pragma unroll
        for (int kc = 0; kc < 2; kc++) {
            bf16x8 af[4], bfr[4];
            #pragma unroll
            for (int i = 0; i < 4; i++)
                af[i] = *(const bf16x8*)(As + (wm + i * 16 + fr) * SAP + kc * 32 + quad * 8);
            #pragma unroll
            for (int i = 0; i < 4; i++)
                bfr[i] = *(const bf16x8*)(Bs + (wn + i * 16 + fr) * SAP + kc * 32 + quad * 8);
            #pragma unroll
            for (int mi = 0; mi < 4; mi++)
                #pragma unroll
                for (int ni = 0; ni < 4; ni++)
                    acc[mi][ni] = __builtin_amdgcn_mfma_f32_16x16x32_bf16(
                        af[mi], bfr[ni], acc[mi][ni], 0, 0, 0);
        }
        __syncthreads();
    }
}

// General GEMM: C = act(A @ Bt^T + bias). Optional fp32 C and/or bf16 Cbf out.
__global__ __launch_bounds__(256) void gemm_mfma(
    const short* __restrict__ A, const short* __restrict__ A2, int lda, int ksplit,
    const short* __restrict__ Bt, const float* __restrict__ bias,
    float* __restrict__ C, int ldc, short* __restrict__ Cbf, int ldcbf,
    int M, int K, int act)
{
    __shared__ short As[128 * SAP];
    __shared__ short Bs[128 * SAP];
    f32x4 acc[4][4];
    #pragma unroll
    for (int i = 0; i < 4; i++)
        #pragma unroll
        for (int j = 0; j < 4; j++) acc[i][j] = (f32x4){0.f, 0.f, 0.f, 0.f};
    int m0 = blockIdx.y * 128, n0 = blockIdx.x * 128;
    mfma_core(A, A2, lda, ksplit, Bt, M, K, m0, n0, As, Bs, acc);
    const int lane = threadIdx.x & 63, wave = threadIdx.x >> 6;
    const int wm = (wave >> 1) << 6, wn = (wave & 1) << 6;
    const int fr = lane & 15, quad = lane >> 4;
    #pragma unroll
    for (int ni = 0; ni < 4; ni++) {
        int gc = n0 + wn + ni * 16 + fr;
        float b = bias[gc];
        #pragma unroll
        for (int mi = 0; mi < 4; mi++) {
            #pragma unroll
            for (int reg = 0; reg < 4; reg++) {
                int gr = m0 + wm + mi * 16 + quad * 4 + reg;
                if (gr >= M) continue;
                float v = acc[mi][ni][reg] + b;
                if (act == 1) v = (v >= 0.f) ? v : 0.01f * v;
                if (C)   C[(size_t)gr * ldc + gc] = v;
                if (Cbf) Cbf[(size_t)gr * ldcbf + gc] = (short)f2bf(v);
            }
        }
    }
}

// Gate: Z = sigmoid([U|h] @ gW + gb); Hm = tanh(U)*Z + h*(1-Z). Writes f32+bf16.
__global__ __launch_bounds__(256) void gate_mfma(
    const short* __restrict__ Ubf, const short* __restrict__ Hbf,
    const short* __restrict__ gWt, const float* __restrict__ gb,
    const float* __restrict__ Uf, const float* __restrict__ Hf,
    float* __restrict__ HmOut, short* __restrict__ HmBf,  // pre-offset r*128, ld 384
    int M)
{
    __shared__ short As[128 * SAP];
    __shared__ short Bs[128 * SAP];
    f32x4 acc[4][4];
    #pragma unroll
    for (int i = 0; i < 4; i++)
        #pragma unroll
        for (int j = 0; j < 4; j++) acc[i][j] = (f32x4){0.f, 0.f, 0.f, 0.f};
    int m0 = blockIdx.y * 128;
    mfma_core(Ubf, Hbf, 128, 128, gWt, M, 256, m0, 0, As, Bs, acc);
    const int lane = threadIdx.x & 63, wave = threadIdx.x >> 6;
    const int wm = (wave >> 1) << 6, wn = (wave & 1) << 6;
    const int fr = lane & 15, quad = lane >> 4;
    #pragma unroll
    for (int ni = 0; ni < 4; ni++) {
        int gc = wn + ni * 16 + fr;
        float b = gb[gc];
        #pragma unroll
        for (int mi = 0; mi < 4; mi++) {
            #pragma unroll
            for (int reg = 0; reg < 4; reg++) {
                int gr = m0 + wm + mi * 16 + quad * 4 + reg;
                if (gr >= M) continue;
                float g = acc[mi][ni][reg] + b;
                float z = 1.f / (1.f + __expf(-g));
                float u = Uf[(size_t)gr * 128 + gc];
                float hh = Hf[(size_t)gr * 128 + gc];
                float val = tanhf(u) * z + hh * (1.f - z);
                HmOut[(size_t)gr * 384 + gc] = val;
                HmBf[(size_t)gr * 384 + gc] = (short)f2bf(val);
            }
        }
    }
}

// Semantic: scores[h*3+r] += sum tanh(Hm[:,r] @ sW1[h] + sb1[h]) . sw2[h]
__global__ __launch_bounds__(256) void semantic_mfma(
    const short* __restrict__ HmBf, const short* __restrict__ sW1t,
    const float* __restrict__ sb1, const float* __restrict__ sw2,
    float* __restrict__ scores, int M)
{
    __shared__ short As[128 * SAP];
    __shared__ short Bs[128 * SAP];
    __shared__ float red[256];
    f32x4 acc[4][4];
    #pragma unroll
    for (int i = 0; i < 4; i++)
        #pragma unroll
        for (int j = 0; j < 4; j++) acc[i][j] = (f32x4){0.f, 0.f, 0.f, 0.f};
    int head = blockIdx.x, r = blockIdx.z;
    int m0 = blockIdx.y * 128, n0 = head * 128;
    mfma_core(HmBf + r * 128, HmBf + r * 128, 384, KBIG, sW1t, M, 128, m0, n0, As, Bs, acc);
    const int lane = threadIdx.x & 63, wave = threadIdx.x >> 6;
    const int wm = (wave >> 1) << 6, wn = (wave & 1) << 6;
    const int fr = lane & 15, quad = lane >> 4;
    float local = 0.f;
    #pragma unroll
    for (int ni = 0; ni < 4; ni++) {
        int gc = n0 + wn + ni * 16 + fr;
        float b = sb1[gc], w2 = sw2[gc];
        #pragma unroll
        for (int mi = 0; mi < 4; mi++) {
            #pragma unroll
            for (int reg = 0; reg < 4; reg++) {
                int gr = m0 + wm + mi * 16 + quad * 4 + reg;
                if (gr >= M) continue;
                local += tanhf(acc[mi][ni][reg] + b) * w2;
            }
        }
    }
    int t = threadIdx.x;
    red[t] = local;
    __syncthreads();
    for (int s = 128; s > 0; s >>= 1) {
        if (t < s) red[t] += red[t + s];
        __syncthreads();
    }
    if (t == 0) atomicAdd(&scores[head * 3 + r], red[0]);
}

__global__ void compute_w_kernel(const float* __restrict__ scores, float* __restrict__ w, float invN)
{
    if (blockIdx.x == 0 && threadIdx.x == 0) {
        float wr[3] = {0.f, 0.f, 0.f};
        for (int h = 0; h < 4; h++) {
            float s0 = scores[h * 3 + 0] * invN;
            float s1 = scores[h * 3 + 1] * invN;
            float s2 = scores[h * 3 + 2] * invN;
            float mx = fmaxf(s0, fmaxf(s1, s2));
            float e0 = __expf(s0 - mx), e1 = __expf(s1 - mx), e2 = __expf(s2 - mx);
            float inv = 1.f / (e0 + e1 + e2);
            wr[0] += 0.25f * e0 * inv;
            wr[1] += 0.25f * e1 * inv;
            wr[2] += 0.25f * e2 * inv;
        }
        w[0] = wr[0]; w[1] = wr[1]; w[2] = wr[2];
    }
}

__global__ void mix_kernel(const float* __restrict__ Hm, const float* __restrict__ w,
                           float* __restrict__ h, short* __restrict__ hbf, int total)
{
    int i = blockIdx.x * blockDim.x + threadIdx.x;
    if (i >= total) return;
    int n = i >> 7, c = i & 127;
    const float* row = Hm + (size_t)n * 384;
    float v = w[0] * row[c] + w[1] * row[128 + c] + w[2] * row[256 + c];
    h[i] = v;
    hbf[i] = (short)f2bf(v);
}

// --------------------------- conversions -----------------------------------
__global__ void convert_bf16_kernel(const float* __restrict__ src, unsigned* __restrict__ dst, int n_pairs)
{
    int i = blockIdx.x * blockDim.x + threadIdx.x;
    if (i >= n_pairs) return;
    float2 f = ((const float2*)src)[i];
    dst[i] = ((unsigned)f2bf(f.y) << 16) | (unsigned)f2bf(f.x);
}

// lin1_W [768,128] -> lin1Wt [128][768]; lin2_W [128,128] -> lin2Wt [128][128]
__global__ void prep_global_kernel(const float* __restrict__ lin1_W, const float* __restrict__ lin2_W,
                                   short* __restrict__ lin1Wt, short* __restrict__ lin2Wt)
{
    int id = blockIdx.x * blockDim.x + threadIdx.x;
    if (id < 98304) {
        int n = id / 768, k = id % 768;
        lin1Wt[id] = (short)f2bf(lin1_W[k * 128 + n]);
    } else if (id < 114688) {
        int r = id - 98304;
        int n = r / 128, k = r % 128;
        lin2Wt[r] = (short)f2bf(lin2_W[k * 128 + n]);
    }
}

// Per-layer weight prep: qkvWt [3][1536][128], wsT [3][128][128],
// gWt [128][256], sW1t [512][128], qkvB [3][1536]
__global__ void prep_layer_kernel(
    const float* __restrict__ Wq, const float* __restrict__ Wk, const float* __restrict__ Wv,
    const float* __restrict__ Ws, const float* __restrict__ bq, const float* __restrict__ bk,
    const float* __restrict__ bv, const float* __restrict__ gW, const float* __restrict__ sW1,
    short* __restrict__ qkvWt, short* __restrict__ wsT, short* __restrict__ gWt,
    short* __restrict__ sW1t, float* __restrict__ qkvB)
{
    const int S0 = 589824, S1 = 638976, S2 = 671744, S3 = 737280, S4 = 741888;
    int id = blockIdx.x * blockDim.x + threadIdx.x;
    if (id < S0) {
        int r = id / (1536 * 128), rem = id % (1536 * 128);
        int n = rem / 128, k = rem % 128;
        float v;
        if (n < 512)       v = Wq[(size_t)r * 65536 + k * 512 + n];
        else if (n < 1024) v = Wk[(size_t)r * 65536 + k * 512 + (n - 512)];
        else               v = Wv[(size_t)r * 65536 + k * 512 + (n - 1024)];
        qkvWt[id] = (short)f2bf(v);
    } else if (id < S1) {
        int q = id - S0;
        int r = q / 16384, rem = q % 16384;
        int n = rem / 128, k = rem % 128;
        wsT[q] = (short)f2bf(Ws[(size_t)r * 16384 + k * 128 + n]);
    } else if (id < S2) {
        int q = id - S1;
        int n = q / 256, k = q % 256;
        gWt[q] = (short)f2bf(gW[k * 128 + n]);
    } else if (id < S3) {
        int q = id - S2;
        int h = q / 16384, rem = q % 16384;
        int n = rem / 128, k = rem % 128;
        sW1t[q] = (short)f2bf(sW1[(size_t)h * 16384 + k * 128 + n]);
    } else if (id < S4) {
        int q = id - S3;
        int r = q / 1536, n = q % 1536;
        float v;
        if (n < 512)       v = bq[r * 512 + n];
        else if (n < 1024) v = bk[r * 512 + (n - 512)];
        else               v = bv[r * 512 + (n - 1024)];
        qkvB[q] = v;
    }
}

// --------------------------- CSR build ------------------------------------
__global__ void zero_i32_kernel(int* __restrict__ p, int n)
{
    int i = blockIdx.x * blockDim.x + threadIdx.x;
    if (i < n) p[i] = 0;
}

__global__ void hist_kernel(const int* __restrict__ dst, int E, int* __restrict__ cnt)
{
    int e = blockIdx.x * blockDim.x + threadIdx.x;
    if (e < E) atomicAdd(&cnt[dst[e]], 1);
}

__global__ __launch_bounds__(1024) void scan_kernel(const int* __restrict__ cnt,
                                                    int* __restrict__ rowptr, int n)
{
    __shared__ int part[1024];
    int tid = threadIdx.x;
    int per = (n + 1023) >> 10;
    int base = tid * per;
    int s = 0;
    for (int i = 0; i < per; i++) {
        int idx = base + i;
        if (idx < n) s += cnt[idx];
    }
    part[tid] = s;
    __syncthreads();
    for (int off = 1; off < 1024; off <<= 1) {
        int val = (tid >= off) ? part[tid - off] : 0;
        __syncthreads();
        part[tid] += val;
        __syncthreads();
    }
    int excl = (tid == 0) ? 0 : part[tid - 1];
    for (int i = 0; i < per; i++) {
        int idx = base + i;
        if (idx < n) { rowptr[idx] = excl; excl += cnt[idx]; }
    }
    if (tid == 1023) rowptr[n] = part[1023];
}

__global__ void scatter_kernel(const int* __restrict__ esrc, const int* __restrict__ edst, int E,
                               const int* __restrict__ rowptr, int* __restrict__ fill,
                               int* __restrict__ col)
{
    int e = blockIdx.x * blockDim.x + threadIdx.x;
    if (e < E) {
        int d = edst[e];
        int pos = rowptr[d] + atomicAdd(&fill[d], 1);
        col[pos] = esrc[e];
    }
}

// --------------------------- attention ------------------------------------
// One wave per dst node. qkv bf16 [N, 1536] (q|k|v). S fp32 [N,128] in/out (U).
__global__ __launch_bounds__(256) void attn_kernel(
    const short* __restrict__ qkv,
    const int* __restrict__ rowptr, const int* __restrict__ colb,
    float* __restrict__ S, short* __restrict__ Ubf, int N)
{
    int wid = ((blockIdx.x * blockDim.x + threadIdx.x) >> 6);
    int lane = threadIdx.x & 63;
    if (wid >= N) return;
    int n = wid;
    int beg = rowptr[n], end = rowptr[n + 1];

    float qf[8];
    const short* qrow = qkv + (size_t)n * 1536;
    #pragma unroll
    for (int j = 0; j < 8; j++) qf[j] = bf2f(qrow[j * 64 + lane]);

    float m0 = -INFINITY, m1 = -INFINITY, m2 = -INFINITY, m3 = -INFINITY;
    float s0 = 0.f, s1 = 0.f, s2 = 0.f, s3 = 0.f;
    float acc[8] = {0.f, 0.f, 0.f, 0.f, 0.f, 0.f, 0.f, 0.f};
    const float scale = 0.088388347648318447f; // 1/sqrt(128)

    for (int i = beg; i < end; i++) {
        int src = colb[i];
        const short* krow = qkv + (size_t)src * 1536 + 512;
        const short* vrow = qkv + (size_t)src * 1536 + 1024;
        float kf[8], vf[8];
        #pragma unroll
        for (int j = 0; j < 8; j++) kf[j] = bf2f(krow[j * 64 + lane]);
        #pragma unroll
        for (int j = 0; j < 8; j++) vf[j] = bf2f(vrow[j * 64 + lane]);
        float p0 = qf[0] * kf[0] + qf[1] * kf[1];
        float p1 = qf[2] * kf[2] + qf[3] * kf[3];
        float p2 = qf[4] * kf[4] + qf[5] * kf[5];
        float p3 = qf[6] * kf[6] + qf[7] * kf[7];
        #pragma unroll
        for (int off = 32; off > 0; off >>= 1) {
            p0 += __shfl_xor(p0, off);
            p1 += __shfl_xor(p1, off);
            p2 += __shfl_xor(p2, off);
            p3 += __shfl_xor(p3, off);
        }
        float l0 = p0 * scale, l1 = p1 * scale, l2 = p2 * scale, l3 = p3 * scale;

        float nm, sc, pe;
        nm = fmaxf(m0, l0); sc = __expf(m0 - nm); pe = __expf(l0 - nm);
        s0 = s0 * sc + pe; acc[0] = acc[0] * sc + pe * vf[0]; acc[1] = acc[1] * sc + pe * vf[1]; m0 = nm;
        nm = fmaxf(m1, l1); sc = __expf(m1 - nm); pe = __expf(l1 - nm);
        s1 = s1 * sc + pe; acc[2] = acc[2] * sc + pe * vf[2]; acc[3] = acc[3] * sc + pe * vf[3]; m1 = nm;
        nm = fmaxf(m2, l2); sc = __expf(m2 - nm); pe = __expf(l2 - nm);
        s2 = s2 * sc + pe; acc[4] = acc[4] * sc + pe * vf[4]; acc[5] = acc[5] * sc + pe * vf[5]; m2 = nm;
        nm = fmaxf(m3, l3); sc = __expf(m3 - nm); pe = __expf(l3 - nm);
        s3 = s3 * sc + pe; acc[6] = acc[6] * sc + pe * vf[6]; acc[7] = acc[7] * sc + pe * vf[7]; m3 = nm;
    }

    float i0 = (s0 > 0.f) ? 1.f / s0 : 0.f;
    float i1 = (s1 > 0.f) ? 1.f / s1 : 0.f;
    float i2 = (s2 > 0.f) ? 1.f / s2 : 0.f;
    float i3 = (s3 > 0.f) ? 1.f / s3 : 0.f;
    float u_lo = 0.25f * (acc[0] * i0 + acc[2] * i1 + acc[4] * i2 + acc[6] * i3);
    float u_hi = 0.25f * (acc[1] * i0 + acc[3] * i1 + acc[5] * i2 + acc[7] * i3);
    float* srow = S + (size_t)n * 128;
    float flo = srow[lane] + u_lo;
    float fhi = srow[64 + lane] + u_hi;
    srow[lane] = flo;
    srow[64 + lane] = fhi;
    Ubf[(size_t)n * 128 + lane] = (short)f2bf(flo);
    Ubf[(size_t)n * 128 + 64 + lane] = (short)f2bf(fhi);
}

// --------------------------- classifier -----------------------------------
__global__ void clf_kernel(const float* __restrict__ t, const float* __restrict__ W,
                           const float* __restrict__ b, float* __restrict__ out, int M)
{
    int n = blockIdx.x * blockDim.x + threadIdx.x;
    if (n >= M) return;
    const float* row = t + (size_t)n * 128;
    float a0 = b[0], a1 = b[1];
    #pragma unroll
    for (int kk = 0; kk < 128; kk++) {
        float a = row[kk];
        a0 += a * W[kk * 2];
        a1 += a * W[kk * 2 + 1];
    }
    out[n * 2] = a0;
    out[n * 2 + 1] = a1;
}

// ---------------------------------------------------------------------------
extern "C" void kernel_launch(void* const* d_in, const int* in_sizes, int n_in,
                              void* d_out, int out_size, void* d_ws, size_t ws_size,
                              hipStream_t stream)
{
    const float* x      = (const float*)d_in[0];
    const int*   edges  = (const int*)d_in[1];
    const float* lin1_W = (const float*)d_in[2];
    const float* lin1_b = (const float*)d_in[3];
    const int L0 = 4, L1 = 17;
    const float* lin2_W = (const float*)d_in[30];
    const float* lin2_b = (const float*)d_in[31];
    const float* clf_W  = (const float*)d_in[32];
    const float* clf_b  = (const float*)d_in[33];
    float* out = (float*)d_out;

    char* w = (char*)d_ws;
    size_t off = 0;
    auto alloc = [&](size_t bytes) { void* p = w + off; off = (off + bytes + 255) & ~(size_t)255; return p; };
    float* h      = (float*)alloc((size_t)Nn * 128 * 4);
    short* h_bf   = (short*)alloc((size_t)Nn * 128 * 2);
    short* x_bf   = (short*)alloc((size_t)Nn * 768 * 2);
    short* qkv_bf = (short*)alloc((size_t)Nn * 1536 * 2);
    float* Sb     = (float*)alloc((size_t)Nn * 128 * 4);
    short* U_bf   = (short*)alloc((size_t)Nn * 128 * 2);
    float* Hm     = (float*)alloc((size_t)Nn * 384 * 4);
    short* Hm_bf  = (short*)alloc((size_t)Nn * 384 * 2);
    short* lin1Wt = (short*)alloc((size_t)98304 * 2);
    short* lin2Wt = (short*)alloc((size_t)16384 * 2);
    short* qkvWt  = (short*)alloc((size_t)2 * 589824 * 2);
    short* wsT    = (short*)alloc((size_t)2 * 49152 * 2);
    short* gWt    = (short*)alloc((size_t)2 * 32768 * 2);
    short* sW1t   = (short*)alloc((size_t)2 * 65536 * 2);
    float* qkvB   = (float*)alloc((size_t)2 * 4608 * 4);
    int* rowptr   = (int*)alloc((size_t)(Nn + 1) * 4);
    int* cnt      = (int*)alloc((size_t)Nn * 4);
    int* colb     = (int*)alloc((size_t)EE * 4);
    float* scores = (float*)alloc(12 * 4);
    float* wmix   = (float*)alloc(3 * 4);

    const int MT = (Nn + 127) / 128;    // 235
    dim3 blk(256);

    // ---- prep: conversions / transposes ----
    {
        int n_pairs = Nn * 768 / 2;
        convert_bf16_kernel<<<(n_pairs + 255) / 256, blk, 0, stream>>>(x, (unsigned*)x_bf, n_pairs);
        prep_global_kernel<<<(114688 + 255) / 256, blk, 0, stream>>>(lin1_W, lin2_W, lin1Wt, lin2Wt);
        for (int l = 0; l < 2; l++) {
            int base = (l == 0) ? L0 : L1;
            prep_layer_kernel<<<(741888 + 255) / 256, blk, 0, stream>>>(
                (const float*)d_in[base + 0], (const float*)d_in[base + 2], (const float*)d_in[base + 4],
                (const float*)d_in[base + 6], (const float*)d_in[base + 1], (const float*)d_in[base + 3],
                (const float*)d_in[base + 5], (const float*)d_in[base + 8], (const float*)d_in[base + 10],
                qkvWt + (size_t)l * 589824, wsT + (size_t)l * 49152, gWt + (size_t)l * 32768,
                sW1t + (size_t)l * 65536, qkvB + (size_t)l * 4608);
        }
    }

    // lin1: h = lrelu(x @ lin1_W + b)
    gemm_mfma<<<dim3(1, MT), blk, 0, stream>>>(
        x_bf, x_bf, 768, KBIG, lin1Wt, lin1_b, h, 128, h_bf, 128, Nn, 768, 1);

    for (int l = 0; l < 2; l++) {
        int base = (l == 0) ? L0 : L1;
        const float* bs  = (const float*)d_in[base + 7];
        const float* gb  = (const float*)d_in[base + 9];
        const float* sb1 = (const float*)d_in[base + 11];
        const float* sw2 = (const float*)d_in[base + 12];
        short* lqkvWt = qkvWt + (size_t)l * 589824;
        short* lwsT   = wsT + (size_t)l * 49152;
        short* lgWt   = gWt + (size_t)l * 32768;
        short* lsW1t  = sW1t + (size_t)l * 65536;
        float* lqkvB  = qkvB + (size_t)l * 4608;

        for (int r = 0; r < RR; r++) {
            // q|k|v GEMM -> bf16 [N,1536]
            gemm_mfma<<<dim3(12, MT), blk, 0, stream>>>(
                h_bf, h_bf, 128, KBIG, lqkvWt + (size_t)r * 196608, lqkvB + r * 1536,
                (float*)nullptr, 0, qkv_bf, 1536, Nn, 128, 0);
            // S = h @ Ws + bs -> fp32
            gemm_mfma<<<dim3(1, MT), blk, 0, stream>>>(
                h_bf, h_bf, 128, KBIG, lwsT + (size_t)r * 16384, bs + r * 128,
                Sb, 128, (short*)nullptr, 0, Nn, 128, 0);

            // CSR build by dst
            const int* esrc = edges + (size_t)r * 2 * EE;
            const int* edst = esrc + EE;
            zero_i32_kernel<<<(Nn + 255) / 256, blk, 0, stream>>>(cnt, Nn);
            hist_kernel<<<(EE + 255) / 256, blk, 0, stream>>>(edst, EE, cnt);
            scan_kernel<<<1, 1024, 0, stream>>>(cnt, rowptr, Nn);
            zero_i32_kernel<<<(Nn + 255) / 256, blk, 0, stream>>>(cnt, Nn);
            scatter_kernel<<<(EE + 255) / 256, blk, 0, stream>>>(esrc, edst, EE, rowptr, cnt, colb);

            // attention: U = mean-head agg + S (in place in Sb), writes U bf16 too
            attn_kernel<<<(Nn + 3) / 4, blk, 0, stream>>>(qkv_bf, rowptr, colb, Sb, U_bf, Nn);

            // gate + combine -> Hm[:, r, :] (fp32 + bf16)
            gate_mfma<<<dim3(1, MT), blk, 0, stream>>>(
                U_bf, h_bf, lgWt, gb, Sb, h, Hm + r * 128, Hm_bf + r * 128, Nn);
        }

        // semantic attention
        zero_i32_kernel<<<1, 64, 0, stream>>>((int*)scores, 12);
        semantic_mfma<<<dim3(4, MT, 3), blk, 0, stream>>>(Hm_bf, lsW1t, sb1, sw2, scores, Nn);
        compute_w_kernel<<<1, 64, 0, stream>>>(scores, wmix, 1.f / (float)Nn);
        mix_kernel<<<(Nn * 128 + 255) / 256, blk, 0, stream>>>(Hm, wmix, h, h_bf, Nn * 128);
    }

    // lin2 + lrelu -> Sb
    gemm_mfma<<<dim3(1, MT), blk, 0, stream>>>(
        h_bf, h_bf, 128, KBIG, lin2Wt, lin2_b, Sb, 128, (short*)nullptr, 0, Nn, 128, 1);
    // classifier
    clf_kernel<<<(Nn + 255) / 256, blk, 0, stream>>>(Sb, clf_W, clf_b, out, Nn);
}

// Round 3
// 1224.377 us; speedup vs baseline: 2.2162x; 1.4700x over previous
//
#include <hip/hip_runtime.h>
#include <math.h>

#define Nn 30000
#define RR 3
#define EE 80000

#define SAP 72        // padded LDS row stride (bf16 elems) for staged tiles
#define EP_LD 68      // epilogue scratch stride (floats)
#define KBIG 0x40000000

typedef __attribute__((ext_vector_type(8))) short bf16x8;
typedef __attribute__((ext_vector_type(4))) float f32x4;

__device__ __forceinline__ unsigned short f2bf(float f) {
    union { float f; unsigned u; } v; v.f = f;
    unsigned r = v.u + 0x7fff + ((v.u >> 16) & 1);
    return (unsigned short)(r >> 16);
}
__device__ __forceinline__ float bf2f(short h) {
    union { unsigned u; float f; } v;
    v.u = ((unsigned)(unsigned short)h) << 16;
    return v.f;
}

// ---------------------------------------------------------------------------
// MFMA GEMM core. A: bf16 row-major, K split at ksplit -> A2 (separate lda).
// Bt: bf16 [N, K] row-major (pre-transposed). Block tile 128x128, BK=64.
// 4 waves, each 64x64 via 4x4 grid of 16x16x32 MFMAs.
// ---------------------------------------------------------------------------
__device__ __forceinline__ void mfma_core(
    const short* __restrict__ A, int lda,
    const short* __restrict__ A2, int lda2, int ksplit,
    const short* __restrict__ Bt,
    int M, int K, int m0, int n0,
    short* As, short* Bs, f32x4 (&acc)[4][4])
{
    const int t = threadIdx.x;
    const int srow = t >> 3;          // 0..31
    const int scol = (t & 7) << 3;    // 0..56 step 8
    const int lane = t & 63;
    const int wave = t >> 6;
    const int wm = (wave >> 1) << 6;
    const int wn = (wave & 1) << 6;
    const int fr = lane & 15;
    const int quad = lane >> 4;

    for (int k0 = 0; k0 < K; k0 += 64) {
        const short* Abase; int kk0, ldax;
        if (k0 < ksplit) { Abase = A;  kk0 = k0;          ldax = lda;  }
        else             { Abase = A2; kk0 = k0 - ksplit; ldax = lda2; }
        #pragma unroll
        for (int rr = 0; rr < 4; rr++) {
            int r = srow + rr * 32;
            int gr = m0 + r;
            bf16x8 va = {0, 0, 0, 0, 0, 0, 0, 0};
            if (gr < M) va = *(const bf16x8*)(Abase + (size_t)gr * ldax + kk0 + scol);
            *(bf16x8*)(As + r * SAP + scol) = va;
        }
        #pragma unroll
        for (int rr = 0; rr < 4; rr++) {
            int r = srow + rr * 32;
            bf16x8 vb = *(const bf16x8*)(Bt + (size_t)(n0 + r) * K + k0 + scol);
            *(bf16x8*)(Bs + r * SAP + scol) = vb;
        }
        __syncthreads();
        #pragma unroll
        for (int kc = 0; kc < 2; kc++) {
            bf16x8 af[4], bfr[4];
            #pragma unroll
            for (int i = 0; i < 4; i++)
                af[i] = *(const bf16x8*)(As + (wm + i * 16 + fr) * SAP + kc * 32 + quad * 8);
            #pragma unroll
            for (int i = 0; i < 4; i++)
                bfr[i] = *(const bf16x8*)(Bs + (wn + i * 16 + fr) * SAP + kc * 32 + quad * 8);
            #pragma unroll
            for (int mi = 0; mi < 4; mi++)
                #pragma unroll
                for (int ni = 0; ni < 4; ni++)
                    acc[mi][ni] = __builtin_amdgcn_mfma_f32_16x16x32_bf16(
                        af[mi], bfr[ni], acc[mi][ni], 0, 0, 0);
        }
        __syncthreads();
    }
}

// General GEMM: C = act(A @ Bt^T + bias). LDS-repacked coalesced epilogue.
__global__ __launch_bounds__(256) void gemm_mfma(
    const short* __restrict__ A, int lda,
    const short* __restrict__ A2, int lda2, int ksplit,
    const short* __restrict__ Bt, const float* __restrict__ bias,
    float* __restrict__ C, int ldc, short* __restrict__ Cbf, int ldcbf,
    int M, int K, int act)
{
    __shared__ short As[128 * SAP];
    __shared__ short Bs[128 * SAP];
    f32x4 acc[4][4];
    #pragma unroll
    for (int i = 0; i < 4; i++)
        #pragma unroll
        for (int j = 0; j < 4; j++) acc[i][j] = (f32x4){0.f, 0.f, 0.f, 0.f};
    int m0 = blockIdx.y * 128, n0 = blockIdx.x * 128;
    mfma_core(A, lda, A2, lda2, ksplit, Bt, M, K, m0, n0, As, Bs, acc);

    const int t = threadIdx.x;
    const int lane = t & 63, wave = t >> 6;
    const int wm = (wave >> 1) << 6, wn = (wave & 1) << 6;
    const int fr = lane & 15, quad = lane >> 4;
    float* ws = (float*)As + wave * 16 * EP_LD;
    const int rrow = lane >> 2;
    const int cseg = (lane & 3) << 4;
    #pragma unroll
    for (int mi = 0; mi < 4; mi++) {
        __syncthreads();
        #pragma unroll
        for (int ni = 0; ni < 4; ni++)
            #pragma unroll
            for (int reg = 0; reg < 4; reg++)
                ws[(quad * 4 + reg) * EP_LD + ni * 16 + fr] = acc[mi][ni][reg];
        __syncthreads();
        int gr = m0 + wm + mi * 16 + rrow;
        if (gr >= M) continue;
        int gc = n0 + wn + cseg;
        float vals[16];
        #pragma unroll
        for (int j = 0; j < 16; j++) {
            float v = ws[rrow * EP_LD + cseg + j] + bias[gc + j];
            if (act == 1) v = (v >= 0.f) ? v : 0.01f * v;
            vals[j] = v;
        }
        if (C) {
            float* cp = C + (size_t)gr * ldc + gc;
            #pragma unroll
            for (int j4 = 0; j4 < 4; j4++)
                *(float4*)(cp + j4 * 4) = make_float4(vals[j4 * 4], vals[j4 * 4 + 1],
                                                      vals[j4 * 4 + 2], vals[j4 * 4 + 3]);
        }
        if (Cbf) {
            unsigned pk[8];
            #pragma unroll
            for (int j2 = 0; j2 < 8; j2++)
                pk[j2] = ((unsigned)f2bf(vals[2 * j2 + 1]) << 16) | (unsigned)f2bf(vals[2 * j2]);
            unsigned* bp = (unsigned*)(Cbf + (size_t)gr * ldcbf + gc);
            *(uint4*)bp       = make_uint4(pk[0], pk[1], pk[2], pk[3]);
            *(uint4*)(bp + 4) = make_uint4(pk[4], pk[5], pk[6], pk[7]);
        }
    }
}

// Gate (z = relation): Z = sigmoid([U_r|h] @ gW + gb); Hm_r = tanh(U_r)*Z + h*(1-Z).
__global__ __launch_bounds__(256) void gate_mfma(
    const short* __restrict__ Ubf,   // [N,384] bf16
    const short* __restrict__ Hbf,   // [N,128] bf16
    const short* __restrict__ gWt, const float* __restrict__ gb,
    const float* __restrict__ Uf,    // [N,384] fp32 (post-attn U)
    const float* __restrict__ Hf,    // [N,128] fp32
    float* __restrict__ Hm, short* __restrict__ HmBf,   // [N,384] each
    int M)
{
    __shared__ short As[128 * SAP];
    __shared__ short Bs[128 * SAP];
    f32x4 acc[4][4];
    #pragma unroll
    for (int i = 0; i < 4; i++)
        #pragma unroll
        for (int j = 0; j < 4; j++) acc[i][j] = (f32x4){0.f, 0.f, 0.f, 0.f};
    int r = blockIdx.z;
    int m0 = blockIdx.y * 128;
    mfma_core(Ubf + r * 128, 384, Hbf, 128, 128, gWt, M, 256, m0, 0, As, Bs, acc);

    const int t = threadIdx.x;
    const int lane = t & 63, wave = t >> 6;
    const int wm = (wave >> 1) << 6, wn = (wave & 1) << 6;
    const int fr = lane & 15, quad = lane >> 4;
    float* ws = (float*)As + wave * 16 * EP_LD;
    const int rrow = lane >> 2;
    const int cseg = (lane & 3) << 4;
    #pragma unroll
    for (int mi = 0; mi < 4; mi++) {
        __syncthreads();
        #pragma unroll
        for (int ni = 0; ni < 4; ni++)
            #pragma unroll
            for (int reg = 0; reg < 4; reg++)
                ws[(quad * 4 + reg) * EP_LD + ni * 16 + fr] = acc[mi][ni][reg];
        __syncthreads();
        int gr = m0 + wm + mi * 16 + rrow;
        if (gr >= M) continue;
        int gc = wn + cseg;
        const float* up = Uf + (size_t)gr * 384 + r * 128 + gc;
        const float* hp = Hf + (size_t)gr * 128 + gc;
        float vals[16];
        #pragma unroll
        for (int j = 0; j < 16; j++) {
            float g = ws[rrow * EP_LD + cseg + j] + gb[gc + j];
            float z = 1.f / (1.f + __expf(-g));
            vals[j] = tanhf(up[j]) * z + hp[j] * (1.f - z);
        }
        float* cp = Hm + (size_t)gr * 384 + r * 128 + gc;
        #pragma unroll
        for (int j4 = 0; j4 < 4; j4++)
            *(float4*)(cp + j4 * 4) = make_float4(vals[j4 * 4], vals[j4 * 4 + 1],
                                                  vals[j4 * 4 + 2], vals[j4 * 4 + 3]);
        unsigned pk[8];
        #pragma unroll
        for (int j2 = 0; j2 < 8; j2++)
            pk[j2] = ((unsigned)f2bf(vals[2 * j2 + 1]) << 16) | (unsigned)f2bf(vals[2 * j2]);
        unsigned* bp = (unsigned*)(HmBf + (size_t)gr * 384 + r * 128 + gc);
        *(uint4*)bp       = make_uint4(pk[0], pk[1], pk[2], pk[3]);
        *(uint4*)(bp + 4) = make_uint4(pk[4], pk[5], pk[6], pk[7]);
    }
}

// Semantic: scores[h*3+r] += sum tanh(Hm[:,r] @ sW1[h] + sb1[h]) . sw2[h]
__global__ __launch_bounds__(256) void semantic_mfma(
    const short* __restrict__ HmBf, const short* __restrict__ sW1t,
    const float* __restrict__ sb1, const float* __restrict__ sw2,
    float* __restrict__ scores, int M)
{
    __shared__ short As[128 * SAP];
    __shared__ short Bs[128 * SAP];
    __shared__ float red[256];
    f32x4 acc[4][4];
    #pragma unroll
    for (int i = 0; i < 4; i++)
        #pragma unroll
        for (int j = 0; j < 4; j++) acc[i][j] = (f32x4){0.f, 0.f, 0.f, 0.f};
    int head = blockIdx.x, r = blockIdx.z;
    int m0 = blockIdx.y * 128, n0 = head * 128;
    mfma_core(HmBf + r * 128, 384, HmBf + r * 128, 384, KBIG, sW1t, M, 128, m0, n0, As, Bs, acc);
    const int lane = threadIdx.x & 63, wave = threadIdx.x >> 6;
    const int wm = (wave >> 1) << 6, wn = (wave & 1) << 6;
    const int fr = lane & 15, quad = lane >> 4;
    float local = 0.f;
    #pragma unroll
    for (int ni = 0; ni < 4; ni++) {
        int gc = n0 + wn + ni * 16 + fr;
        float b = sb1[gc], w2 = sw2[gc];
        #pragma unroll
        for (int mi = 0; mi < 4; mi++) {
            #pragma unroll
            for (int reg = 0; reg < 4; reg++) {
                int gr = m0 + wm + mi * 16 + quad * 4 + reg;
                if (gr >= M) continue;
                local += tanhf(acc[mi][ni][reg] + b) * w2;
            }
        }
    }
    int t = threadIdx.x;
    red[t] = local;
    __syncthreads();
    for (int s = 128; s > 0; s >>= 1) {
        if (t < s) red[t] += red[t + s];
        __syncthreads();
    }
    if (t == 0) atomicAdd(&scores[head * 3 + r], red[0]);
}

__global__ void compute_w_kernel(const float* __restrict__ scores, float* __restrict__ w, float invN)
{
    if (blockIdx.x == 0 && threadIdx.x == 0) {
        float wr[3] = {0.f, 0.f, 0.f};
        for (int h = 0; h < 4; h++) {
            float s0 = scores[h * 3 + 0] * invN;
            float s1 = scores[h * 3 + 1] * invN;
            float s2 = scores[h * 3 + 2] * invN;
            float mx = fmaxf(s0, fmaxf(s1, s2));
            float e0 = __expf(s0 - mx), e1 = __expf(s1 - mx), e2 = __expf(s2 - mx);
            float inv = 1.f / (e0 + e1 + e2);
            wr[0] += 0.25f * e0 * inv;
            wr[1] += 0.25f * e1 * inv;
            wr[2] += 0.25f * e2 * inv;
        }
        w[0] = wr[0]; w[1] = wr[1]; w[2] = wr[2];
    }
}

__global__ void mix_kernel(const float* __restrict__ Hm, const float* __restrict__ w,
                           float* __restrict__ h, short* __restrict__ hbf, int total)
{
    int i = blockIdx.x * blockDim.x + threadIdx.x;
    if (i >= total) return;
    int n = i >> 7, c = i & 127;
    const float* row = Hm + (size_t)n * 384;
    float v = w[0] * row[c] + w[1] * row[128 + c] + w[2] * row[256 + c];
    h[i] = v;
    hbf[i] = (short)f2bf(v);
}

// --------------------------- conversions -----------------------------------
__global__ void convert_bf16_kernel(const float* __restrict__ src, unsigned* __restrict__ dst, int n_pairs)
{
    int i = blockIdx.x * blockDim.x + threadIdx.x;
    if (i >= n_pairs) return;
    float2 f = ((const float2*)src)[i];
    dst[i] = ((unsigned)f2bf(f.y) << 16) | (unsigned)f2bf(f.x);
}

__global__ void prep_global_kernel(const float* __restrict__ lin1_W, const float* __restrict__ lin2_W,
                                   short* __restrict__ lin1Wt, short* __restrict__ lin2Wt)
{
    int id = blockIdx.x * blockDim.x + threadIdx.x;
    if (id < 98304) {
        int n = id / 768, k = id % 768;
        lin1Wt[id] = (short)f2bf(lin1_W[k * 128 + n]);
    } else if (id < 114688) {
        int r = id - 98304;
        int n = r / 128, k = r % 128;
        lin2Wt[r] = (short)f2bf(lin2_W[k * 128 + n]);
    }
}

// Per-layer weight prep: qkvWt [3][1536][128], wsT [3][128][128],
// gWt [128][256], sW1t [512][128], qkvB [3][1536]
__global__ void prep_layer_kernel(
    const float* __restrict__ Wq, const float* __restrict__ Wk, const float* __restrict__ Wv,
    const float* __restrict__ Ws, const float* __restrict__ bq, const float* __restrict__ bk,
    const float* __restrict__ bv, const float* __restrict__ gW, const float* __restrict__ sW1,
    short* __restrict__ qkvWt, short* __restrict__ wsT, short* __restrict__ gWt,
    short* __restrict__ sW1t, float* __restrict__ qkvB)
{
    const int S0 = 589824, S1 = 638976, S2 = 671744, S3 = 737280, S4 = 741888;
    int id = blockIdx.x * blockDim.x + threadIdx.x;
    if (id < S0) {
        int r = id / (1536 * 128), rem = id % (1536 * 128);
        int n = rem / 128, k = rem % 128;
        float v;
        if (n < 512)       v = Wq[(size_t)r * 65536 + k * 512 + n];
        else if (n < 1024) v = Wk[(size_t)r * 65536 + k * 512 + (n - 512)];
        else               v = Wv[(size_t)r * 65536 + k * 512 + (n - 1024)];
        qkvWt[id] = (short)f2bf(v);
    } else if (id < S1) {
        int q = id - S0;
        int r = q / 16384, rem = q % 16384;
        int n = rem / 128, k = rem % 128;
        wsT[q] = (short)f2bf(Ws[(size_t)r * 16384 + k * 128 + n]);
    } else if (id < S2) {
        int q = id - S1;
        int n = q / 256, k = q % 256;
        gWt[q] = (short)f2bf(gW[k * 128 + n]);
    } else if (id < S3) {
        int q = id - S2;
        int h = q / 16384, rem = q % 16384;
        int n = rem / 128, k = rem % 128;
        sW1t[q] = (short)f2bf(sW1[(size_t)h * 16384 + k * 128 + n]);
    } else if (id < S4) {
        int q = id - S3;
        int r = q / 1536, n = q % 1536;
        float v;
        if (n < 512)       v = bq[r * 512 + n];
        else if (n < 1024) v = bk[r * 512 + (n - 512)];
        else               v = bv[r * 512 + (n - 1024)];
        qkvB[q] = v;
    }
}

// --------------------------- CSR build (once, all 3 relations) -------------
__global__ void zero_i32_kernel(int* __restrict__ p, int n)
{
    int i = blockIdx.x * blockDim.x + threadIdx.x;
    if (i < n) p[i] = 0;
}

__global__ void hist3_kernel(const int* __restrict__ edges, int* __restrict__ cnt3)
{
    int i = blockIdx.x * blockDim.x + threadIdx.x;
    if (i >= 3 * EE) return;
    int r = i / EE, e = i - r * EE;
    int d = edges[(size_t)r * 2 * EE + EE + e];
    atomicAdd(&cnt3[r * Nn + d], 1);
}

__global__ __launch_bounds__(1024) void scan3_kernel(const int* __restrict__ cnt3,
                                                     int* __restrict__ rowptr3)
{
    __shared__ int part[1024];
    const int r = blockIdx.x;
    const int* cnt = cnt3 + r * Nn;
    int* rowptr = rowptr3 + r * (Nn + 1);
    int tid = threadIdx.x;
    int per = (Nn + 1023) >> 10;
    int base = tid * per;
    int s = 0;
    for (int i = 0; i < per; i++) {
        int idx = base + i;
        if (idx < Nn) s += cnt[idx];
    }
    part[tid] = s;
    __syncthreads();
    for (int off = 1; off < 1024; off <<= 1) {
        int val = (tid >= off) ? part[tid - off] : 0;
        __syncthreads();
        part[tid] += val;
        __syncthreads();
    }
    int excl = (tid == 0) ? 0 : part[tid - 1];
    for (int i = 0; i < per; i++) {
        int idx = base + i;
        if (idx < Nn) { rowptr[idx] = excl; excl += cnt[idx]; }
    }
    if (tid == 1023) rowptr[Nn] = part[1023];
}

__global__ void scatter3_kernel(const int* __restrict__ edges,
                                const int* __restrict__ rowptr3, int* __restrict__ fill3,
                                int* __restrict__ col3)
{
    int i = blockIdx.x * blockDim.x + threadIdx.x;
    if (i >= 3 * EE) return;
    int r = i / EE, e = i - r * EE;
    int src = edges[(size_t)r * 2 * EE + e];
    int d   = edges[(size_t)r * 2 * EE + EE + e];
    int pos = rowptr3[r * (Nn + 1) + d] + atomicAdd(&fill3[r * Nn + d], 1);
    col3[r * EE + pos] = src;
}

// --------------------------- attention ------------------------------------
// One wave per dst node. qkv bf16 [N,1536] (q|k|v). S/Ubf pre-offset by r*128, stride 384.
__global__ __launch_bounds__(256) void attn_kernel(
    const short* __restrict__ qkv,
    const int* __restrict__ rowptr, const int* __restrict__ colb,
    float* __restrict__ S, short* __restrict__ Ubf, int N)
{
    int wid = ((blockIdx.x * blockDim.x + threadIdx.x) >> 6);
    int lane = threadIdx.x & 63;
    if (wid >= N) return;
    int n = wid;
    int beg = rowptr[n], end = rowptr[n + 1];

    float qf[8];
    const short* qrow = qkv + (size_t)n * 1536;
    #pragma unroll
    for (int j = 0; j < 8; j++) qf[j] = bf2f(qrow[j * 64 + lane]);

    float m0 = -INFINITY, m1 = -INFINITY, m2 = -INFINITY, m3 = -INFINITY;
    float s0 = 0.f, s1 = 0.f, s2 = 0.f, s3 = 0.f;
    float acc[8] = {0.f, 0.f, 0.f, 0.f, 0.f, 0.f, 0.f, 0.f};
    const float scale = 0.088388347648318447f; // 1/sqrt(128)

    for (int i = beg; i < end; i++) {
        int src = colb[i];
        const short* krow = qkv + (size_t)src * 1536 + 512;
        const short* vrow = qkv + (size_t)src * 1536 + 1024;
        float kf[8], vf[8];
        #pragma unroll
        for (int j = 0; j < 8; j++) kf[j] = bf2f(krow[j * 64 + lane]);
        #pragma unroll
        for (int j = 0; j < 8; j++) vf[j] = bf2f(vrow[j * 64 + lane]);
        float p0 = qf[0] * kf[0] + qf[1] * kf[1];
        float p1 = qf[2] * kf[2] + qf[3] * kf[3];
        float p2 = qf[4] * kf[4] + qf[5] * kf[5];
        float p3 = qf[6] * kf[6] + qf[7] * kf[7];
        #pragma unroll
        for (int off = 32; off > 0; off >>= 1) {
            p0 += __shfl_xor(p0, off);
            p1 += __shfl_xor(p1, off);
            p2 += __shfl_xor(p2, off);
            p3 += __shfl_xor(p3, off);
        }
        float l0 = p0 * scale, l1 = p1 * scale, l2 = p2 * scale, l3 = p3 * scale;

        float nm, sc, pe;
        nm = fmaxf(m0, l0); sc = __expf(m0 - nm); pe = __expf(l0 - nm);
        s0 = s0 * sc + pe; acc[0] = acc[0] * sc + pe * vf[0]; acc[1] = acc[1] * sc + pe * vf[1]; m0 = nm;
        nm = fmaxf(m1, l1); sc = __expf(m1 - nm); pe = __expf(l1 - nm);
        s1 = s1 * sc + pe; acc[2] = acc[2] * sc + pe * vf[2]; acc[3] = acc[3] * sc + pe * vf[3]; m1 = nm;
        nm = fmaxf(m2, l2); sc = __expf(m2 - nm); pe = __expf(l2 - nm);
        s2 = s2 * sc + pe; acc[4] = acc[4] * sc + pe * vf[4]; acc[5] = acc[5] * sc + pe * vf[5]; m2 = nm;
        nm = fmaxf(m3, l3); sc = __expf(m3 - nm); pe = __expf(l3 - nm);
        s3 = s3 * sc + pe; acc[6] = acc[6] * sc + pe * vf[6]; acc[7] = acc[7] * sc + pe * vf[7]; m3 = nm;
    }

    float i0 = (s0 > 0.f) ? 1.f / s0 : 0.f;
    float i1 = (s1 > 0.f) ? 1.f / s1 : 0.f;
    float i2 = (s2 > 0.f) ? 1.f / s2 : 0.f;
    float i3 = (s3 > 0.f) ? 1.f / s3 : 0.f;
    float u_lo = 0.25f * (acc[0] * i0 + acc[2] * i1 + acc[4] * i2 + acc[6] * i3);
    float u_hi = 0.25f * (acc[1] * i0 + acc[3] * i1 + acc[5] * i2 + acc[7] * i3);
    float* srow = S + (size_t)n * 384;
    float flo = srow[lane] + u_lo;
    float fhi = srow[64 + lane] + u_hi;
    srow[lane] = flo;
    srow[64 + lane] = fhi;
    Ubf[(size_t)n * 384 + lane] = (short)f2bf(flo);
    Ubf[(size_t)n * 384 + 64 + lane] = (short)f2bf(fhi);
}

// --------------------------- classifier -----------------------------------
__global__ void clf_kernel(const float* __restrict__ t, const float* __restrict__ W,
                           const float* __restrict__ b, float* __restrict__ out, int M)
{
    int n = blockIdx.x * blockDim.x + threadIdx.x;
    if (n >= M) return;
    const float* row = t + (size_t)n * 128;
    float a0 = b[0], a1 = b[1];
    #pragma unroll
    for (int kk = 0; kk < 128; kk++) {
        float a = row[kk];
        a0 += a * W[kk * 2];
        a1 += a * W[kk * 2 + 1];
    }
    out[n * 2] = a0;
    out[n * 2 + 1] = a1;
}

// ---------------------------------------------------------------------------
extern "C" void kernel_launch(void* const* d_in, const int* in_sizes, int n_in,
                              void* d_out, int out_size, void* d_ws, size_t ws_size,
                              hipStream_t stream)
{
    const float* x      = (const float*)d_in[0];
    const int*   edges  = (const int*)d_in[1];
    const float* lin1_W = (const float*)d_in[2];
    const float* lin1_b = (const float*)d_in[3];
    const int L0 = 4, L1 = 17;
    const float* lin2_W = (const float*)d_in[30];
    const float* lin2_b = (const float*)d_in[31];
    const float* clf_W  = (const float*)d_in[32];
    const float* clf_b  = (const float*)d_in[33];
    float* out = (float*)d_out;

    char* w = (char*)d_ws;
    size_t off = 0;
    auto alloc = [&](size_t bytes) { void* p = w + off; off = (off + bytes + 255) & ~(size_t)255; return p; };
    float* h      = (float*)alloc((size_t)Nn * 128 * 4);
    short* h_bf   = (short*)alloc((size_t)Nn * 128 * 2);
    // x_bf (46 MB) and qkv_bf (92 MB) are live at disjoint times -> union
    short* qkv_bf = (short*)alloc((size_t)Nn * 1536 * 2);
    short* x_bf   = qkv_bf;
    float* Sb     = (float*)alloc((size_t)Nn * 384 * 4);   // Ws out / U fp32, all 3 relations
    short* U_bf   = (short*)alloc((size_t)Nn * 384 * 2);
    float* Hm     = (float*)alloc((size_t)Nn * 384 * 4);
    short* Hm_bf  = (short*)alloc((size_t)Nn * 384 * 2);
    short* lin1Wt = (short*)alloc((size_t)98304 * 2);
    short* lin2Wt = (short*)alloc((size_t)16384 * 2);
    short* qkvWt  = (short*)alloc((size_t)2 * 589824 * 2);
    short* wsT    = (short*)alloc((size_t)2 * 49152 * 2);
    short* gWt    = (short*)alloc((size_t)2 * 32768 * 2);
    short* sW1t   = (short*)alloc((size_t)2 * 65536 * 2);
    float* qkvB   = (float*)alloc((size_t)2 * 4608 * 4);
    int* rowptr3  = (int*)alloc((size_t)3 * (Nn + 1) * 4);
    int* cnt3     = (int*)alloc((size_t)3 * Nn * 4);
    int* col3     = (int*)alloc((size_t)3 * EE * 4);
    float* scores = (float*)alloc(12 * 4);
    float* wmix   = (float*)alloc(3 * 4);

    const int MT = (Nn + 127) / 128;    // 235
    dim3 blk(256);

    // ---- prep: conversions / transposes / CSR (graph is layer-invariant) ----
    {
        int n_pairs = Nn * 768 / 2;
        convert_bf16_kernel<<<(n_pairs + 255) / 256, blk, 0, stream>>>(x, (unsigned*)x_bf, n_pairs);
        prep_global_kernel<<<(114688 + 255) / 256, blk, 0, stream>>>(lin1_W, lin2_W, lin1Wt, lin2Wt);
        for (int l = 0; l < 2; l++) {
            int base = (l == 0) ? L0 : L1;
            prep_layer_kernel<<<(741888 + 255) / 256, blk, 0, stream>>>(
                (const float*)d_in[base + 0], (const float*)d_in[base + 2], (const float*)d_in[base + 4],
                (const float*)d_in[base + 6], (const float*)d_in[base + 1], (const float*)d_in[base + 3],
                (const float*)d_in[base + 5], (const float*)d_in[base + 8], (const float*)d_in[base + 10],
                qkvWt + (size_t)l * 589824, wsT + (size_t)l * 49152, gWt + (size_t)l * 32768,
                sW1t + (size_t)l * 65536, qkvB + (size_t)l * 4608);
        }
        zero_i32_kernel<<<(3 * Nn + 255) / 256, blk, 0, stream>>>(cnt3, 3 * Nn);
        hist3_kernel<<<(3 * EE + 255) / 256, blk, 0, stream>>>(edges, cnt3);
        scan3_kernel<<<3, 1024, 0, stream>>>(cnt3, rowptr3);
        zero_i32_kernel<<<(3 * Nn + 255) / 256, blk, 0, stream>>>(cnt3, 3 * Nn);
        scatter3_kernel<<<(3 * EE + 255) / 256, blk, 0, stream>>>(edges, rowptr3, cnt3, col3);
    }

    // lin1: h = lrelu(x @ lin1_W + b)  (must finish before qkv_bf overwrites x_bf)
    gemm_mfma<<<dim3(1, MT), blk, 0, stream>>>(
        x_bf, 768, x_bf, 768, KBIG, lin1Wt, lin1_b, h, 128, h_bf, 128, Nn, 768, 1);

    for (int l = 0; l < 2; l++) {
        int base = (l == 0) ? L0 : L1;
        const float* bs_all = (const float*)d_in[base + 7];   // [3,128] = [384]
        const float* gb  = (const float*)d_in[base + 9];
        const float* sb1 = (const float*)d_in[base + 11];
        const float* sw2 = (const float*)d_in[base + 12];
        short* lqkvWt = qkvWt + (size_t)l * 589824;
        short* lwsT   = wsT + (size_t)l * 49152;
        short* lgWt   = gWt + (size_t)l * 32768;
        short* lsW1t  = sW1t + (size_t)l * 65536;
        float* lqkvB  = qkvB + (size_t)l * 4608;

        // S = h @ Ws + bs for all 3 relations -> Sb [N,384]
        gemm_mfma<<<dim3(3, MT), blk, 0, stream>>>(
            h_bf, 128, h_bf, 128, KBIG, lwsT, bs_all,
            Sb, 384, (short*)nullptr, 0, Nn, 128, 0);

        for (int r = 0; r < RR; r++) {
            // q|k|v GEMM -> bf16 [N,1536]
            gemm_mfma<<<dim3(12, MT), blk, 0, stream>>>(
                h_bf, 128, h_bf, 128, KBIG, lqkvWt + (size_t)r * 196608, lqkvB + r * 1536,
                (float*)nullptr, 0, qkv_bf, 1536, Nn, 128, 0);
            // attention: U_r = mean-head agg + S_r (in place in Sb[:, r]), writes U bf16
            attn_kernel<<<(Nn + 3) / 4, blk, 0, stream>>>(
                qkv_bf, rowptr3 + r * (Nn + 1), col3 + r * EE,
                Sb + r * 128, U_bf + r * 128, Nn);
        }

        // gate + combine for all 3 relations -> Hm (fp32 + bf16)
        gate_mfma<<<dim3(1, MT, 3), blk, 0, stream>>>(
            U_bf, h_bf, lgWt, gb, Sb, h, Hm, Hm_bf, Nn);

        // semantic attention
        zero_i32_kernel<<<1, 64, 0, stream>>>((int*)scores, 12);
        semantic_mfma<<<dim3(4, MT, 3), blk, 0, stream>>>(Hm_bf, lsW1t, sb1, sw2, scores, Nn);
        compute_w_kernel<<<1, 64, 0, stream>>>(scores, wmix, 1.f / (float)Nn);
        mix_kernel<<<(Nn * 128 + 255) / 256, blk, 0, stream>>>(Hm, wmix, h, h_bf, Nn * 128);
    }

    // lin2 + lrelu -> Sb (reused, ld 128)
    gemm_mfma<<<dim3(1, MT), blk, 0, stream>>>(
        h_bf, 128, h_bf, 128, KBIG, lin2Wt, lin2_b, Sb, 128, (short*)nullptr, 0, Nn, 128, 1);
    // classifier
    clf_kernel<<<(Nn + 255) / 256, blk, 0, stream>>>(Sb, clf_W, clf_b, out, Nn);
}